// Round 3
// baseline (196.418 us; speedup 1.0000x reference)
//
#include <hip/hip_runtime.h>
#include <stdint.h>

#define M_DIM 2048
#define N_DIM 4096
#define K_DIM 4096
#define NGROUP 32
#define GSIZE 128

#define RQ_UP   (127.0f / 15.0f)   // weight requant gain
#define RQ_DOWN (15.0f / 127.0f)

// ---------------------------------------------------------------------------
// GEMM geometry: 256x128 tile, 8 waves (512 thr) as 4(M) x 2(N), wave 64x64.
// R3 change: A is loaded DIRECTLY global->VGPR (each lane's MFMA A-fragment is
// a contiguous 16B chunk of row-major A8), double-buffered 2 slices ahead.
// Only B goes through LDS (4 slots x 8 KiB, XOR-swizzled, 0 conflicts).
// Rationale: with both operands in LDS the CU is LDS-bound (960 cyc/slice
// vs 653 MFMA); B-only LDS = 448 cyc/slice -> MFMA-bound.
// One barrier per slice (slot overwrite separated by >= 1 full slice).
// ---------------------------------------------------------------------------
#define BM 256
#define BN 128
#define KSLICE 64
#define NSLICE (K_DIM / KSLICE)    // 64
#define BSLOT (BN * KSLICE)        //  8 KiB

typedef __attribute__((ext_vector_type(4))) int int32x4_t;

static __device__ __forceinline__ void gl2lds16(const void* g, void* l) {
    auto gp = (const __attribute__((address_space(1))) unsigned int*)(uintptr_t)g;
    auto lp = (__attribute__((address_space(3))) unsigned int*)(uintptr_t)l;
    __builtin_amdgcn_global_load_lds(gp, lp, 16, 0, 0);
}

#define WAITVM_(N) asm volatile("s_waitcnt vmcnt(" #N ")" ::: "memory")
#define WAITVM(N) WAITVM_(N)
#define WAITLGKM_(N) asm volatile("s_waitcnt lgkmcnt(" #N ")" ::: "memory")
#define WAITLGKM(N) WAITLGKM_(N)
#define BARRIER() asm volatile("s_barrier" ::: "memory")

// ---------------------------------------------------------------------------
// Fused prep:
//   [0, 2048): per-token activation quant -> A8 = (q-128) int8, xscale, czp
//   [2048, ..): weight requant; rsn computed in-cluster via shfl_xor max.
// ---------------------------------------------------------------------------
#define QUANT_BLOCKS M_DIM
#define DEQ_BLOCKS ((N_DIM * K_DIM) / 8 / 256)       // 8 codes / thread

__global__ __launch_bounds__(256) void prep_kernel(
        const float* __restrict__ x,
        const int* __restrict__ qw,          // [N][K] codes 0..15 as int32
        const float* __restrict__ wsc,       // [N][32]
        const int* __restrict__ wzp,         // [N][32]
        char* __restrict__ A8,               // [M][K] int8 (q-128)
        char* __restrict__ Bt8,              // [N][K] int8 requantized
        float* __restrict__ xscale,          // [M]
        float* __restrict__ xzpc,            // [M]  = 128 - zp
        int* __restrict__ Sw)                // [N][32] group sums of Bt8
{
    const int t = threadIdx.x;
    if (blockIdx.x < QUANT_BLOCKS) {
        const int s = blockIdx.x;
        const float* xrow = x + (size_t)s * K_DIM;

        float xv[16];
        float vmin = 1e38f, vmax = -1e38f;
#pragma unroll
        for (int p = 0; p < 4; ++p) {
            float4 v = *((const float4*)(xrow + p * 1024) + t);
            xv[p*4+0] = v.x; xv[p*4+1] = v.y; xv[p*4+2] = v.z; xv[p*4+3] = v.w;
            vmin = fminf(vmin, fminf(fminf(v.x, v.y), fminf(v.z, v.w)));
            vmax = fmaxf(vmax, fmaxf(fmaxf(v.x, v.y), fmaxf(v.z, v.w)));
        }
#pragma unroll
        for (int off = 32; off > 0; off >>= 1) {
            vmin = fminf(vmin, __shfl_xor(vmin, off));
            vmax = fmaxf(vmax, __shfl_xor(vmax, off));
        }
        __shared__ float smin[4], smax[4];
        const int wave = t >> 6;
        if ((t & 63) == 0) { smin[wave] = vmin; smax[wave] = vmax; }
        __syncthreads();
        vmin = fminf(fminf(smin[0], smin[1]), fminf(smin[2], smin[3]));
        vmax = fmaxf(fmaxf(smax[0], smax[1]), fmaxf(smax[2], smax[3]));

        float sc = (vmax - vmin) / 255.0f;
        sc = fmaxf(sc, 1e-5f);
        float zp = rintf(-vmin / sc);
        zp = fminf(fmaxf(zp, 0.0f), 255.0f);

#pragma unroll
        for (int p = 0; p < 4; ++p) {
            int b[4];
#pragma unroll
            for (int e = 0; e < 4; ++e) {
                float q = fminf(fmaxf(rintf(xv[p*4+e] / sc) + zp, 0.0f), 255.0f);
                b[e] = (int)q - 128;
            }
            unsigned pack = (b[0] & 0xff) | ((b[1] & 0xff) << 8) |
                            ((b[2] & 0xff) << 16) | ((b[3] & 0xff) << 24);
            *(unsigned*)(A8 + (size_t)s * K_DIM + p * 1024 + t * 4) = pack;
        }
        if (t == 0) { xscale[s] = sc; xzpc[s] = 128.0f - zp; }
    } else {
        // ---- weight requant: 8 codes/thread; 16-lane cluster = 1 group ----
        const size_t base = ((size_t)(blockIdx.x - QUANT_BLOCKS) * 256 + t) * 8;
        const int n = (int)(base >> 12);          // /4096
        const int g = (int)((base >> 7) & 31);
        const int zp = wzp[n * NGROUP + g];

        // inline rsn: row max of the 32 scales across the 16-lane cluster
        const int cl = t & 15;
        float2 wp = *(const float2*)(wsc + (size_t)n * NGROUP + cl * 2);
        float smx = fmaxf(wp.x, wp.y);
#pragma unroll
        for (int off = 1; off < 16; off <<= 1)
            smx = fmaxf(smx, __shfl_xor(smx, off));
        const float factor = wsc[n * NGROUP + g] * (RQ_UP / smx);   // <= 127/15

        int4 c0 = *(const int4*)(qw + base);
        int4 c1 = *(const int4*)(qw + base + 4);
        int w[8];
        w[0] = (int)rintf((float)(c0.x - zp) * factor);
        w[1] = (int)rintf((float)(c0.y - zp) * factor);
        w[2] = (int)rintf((float)(c0.z - zp) * factor);
        w[3] = (int)rintf((float)(c0.w - zp) * factor);
        w[4] = (int)rintf((float)(c1.x - zp) * factor);
        w[5] = (int)rintf((float)(c1.y - zp) * factor);
        w[6] = (int)rintf((float)(c1.z - zp) * factor);
        w[7] = (int)rintf((float)(c1.w - zp) * factor);
        uint2 pk;
        pk.x = (w[0] & 0xff) | ((w[1] & 0xff) << 8) | ((w[2] & 0xff) << 16) | ((w[3] & 0xff) << 24);
        pk.y = (w[4] & 0xff) | ((w[5] & 0xff) << 8) | ((w[6] & 0xff) << 16) | ((w[7] & 0xff) << 24);
        *(uint2*)(Bt8 + base) = pk;

        int s8 = w[0] + w[1] + w[2] + w[3] + w[4] + w[5] + w[6] + w[7];
#pragma unroll
        for (int off = 1; off < 16; off <<= 1) s8 += __shfl_xor(s8, off);
        if ((t & 15) == 0)
            Sw[n * NGROUP + g] = s8;     // coalesced, no atomic
    }
}

// ---------------------------------------------------------------------------
// Pipelined i8 GEMM: A direct global->reg (dbuf, distance 2), B via LDS
// (4 slots, distance 3). One barrier per slice; counted vmcnt/lgkmcnt.
// Epilogue: out[m][n] = xscale[m]*(fws[n]*iacc + czp[m]*WSf[n]) + bias[n]
// ---------------------------------------------------------------------------
__global__ __launch_bounds__(512, 1) void gemm_kernel(
        const char* __restrict__ A8,     // [M][K] int8
        const char* __restrict__ Bt8,    // [N][K] int8
        const float* __restrict__ xscale,
        const float* __restrict__ xzpc,
        const float* __restrict__ wsc,   // [N][32]
        const int* __restrict__ Sw,      // [N][32]
        const float* __restrict__ bias,  // [N]
        float* __restrict__ out)         // [M][N] f32
{
    __shared__ __align__(16) char Bs[4][BSLOT];   // 32 KiB
    __shared__ float fws_s[BN], wsf_s[BN];

    const int tid  = threadIdx.x;
    const int bn   = blockIdx.x;         // R1 mapping (41.6 MB FETCH measured)
    const int bm   = blockIdx.y;
    const int wave = tid >> 6;
    const int lane = tid & 63;
    const int wr   = wave >> 1;          // 0..3  -> 64-row band
    const int wcl  = wave & 1;           // 0..1  -> 64-col band
    const int lrow  = lane & 15;
    const int lquad = lane >> 4;         // 0..3 -> 16B k-chunk

    // --- per-column epilogue constants, before the pipeline starts ---
    if (tid < BN) {
        const int n = bn * BN + tid;
        const int4* s4 = (const int4*)(Sw + (size_t)n * NGROUP);
        int acc = 0;
#pragma unroll
        for (int p = 0; p < 8; ++p) { int4 v = s4[p]; acc += v.x + v.y + v.z + v.w; }
        const float4* w4 = (const float4*)(wsc + (size_t)n * NGROUP);
        float s = 0.f;
#pragma unroll
        for (int p = 0; p < 8; ++p) {
            float4 w = w4[p];
            s = fmaxf(s, fmaxf(fmaxf(w.x, w.y), fmaxf(w.z, w.w)));
        }
        const float fw = s * RQ_DOWN;
        fws_s[tid] = fw;
        wsf_s[tid] = fw * (float)acc;
    }
    // drain everything -> clean vmcnt/lgkmcnt baseline for counted waits
    asm volatile("s_waitcnt vmcnt(0) lgkmcnt(0)" ::: "memory");

    // --- B staging addresses: gl2lds dst = uniform base + lane*16 (m104).
    // 16B chunk c of 64B row r stored at slot c ^ ((r>>1)&3)  [0 conflicts].
    const char* Bb = Bt8 + (size_t)(bn * BN) * K_DIM;
    const int lsub = lane >> 2;
    const int csrc = (lane & 3) ^ ((lane >> 3) & 3);
    const char* gB0 = Bb + (size_t)(wave * 16 + lsub) * K_DIM + csrc * 16;
    const int lB0 = wave * 1024;

    // --- A direct-load base: lane's frag i of slice s is the 16B chunk at
    // row (bm*256 + wr*64 + i*16 + lrow), bytes [s*64 + lquad*16, +16). ---
    const char* gA = A8 + (size_t)(bm * BM + wr * 64 + lrow) * K_DIM + lquad * 16;

    // --- ds_read offsets (slot-relative), swizzle matches staging ---
    const int xq = (lquad ^ ((lrow >> 1) & 3)) * 16;
    int boff[4];
#pragma unroll
    for (int j = 0; j < 4; ++j)
        boff[j] = (wcl * 64 + j * 16 + lrow) * KSLICE + xq;

    int32x4_t iacc[4][4];
    const int32x4_t zi = {0, 0, 0, 0};
#pragma unroll
    for (int i = 0; i < 4; ++i)
#pragma unroll
        for (int j = 0; j < 4; ++j) iacc[i][j] = zi;

    int32x4_t aX[4], aY[4], bX[4], bY[4];

#define STAGEB(t) gl2lds16(gB0 + (size_t)(t) * KSLICE, &Bs[(t) & 3][0] + lB0)

#define LOADA(t, ar) {                                                \
        _Pragma("unroll")                                             \
        for (int i_ = 0; i_ < 4; ++i_)                                \
            ar[i_] = *(const int32x4_t*)(gA + (size_t)i_ * 16 * K_DIM \
                                            + (size_t)(t) * KSLICE);  \
    }

#define READB(t, br) {                                                \
        const char* Bp_ = &Bs[(t) & 3][0];                            \
        _Pragma("unroll")                                             \
        for (int j_ = 0; j_ < 4; ++j_)                                \
            br[j_] = *(const int32x4_t*)(Bp_ + boff[j_]);             \
    }

#define MFMAS(ar, br) {                                               \
        __builtin_amdgcn_s_setprio(1);                                \
        _Pragma("unroll")                                             \
        for (int i_ = 0; i_ < 4; ++i_)                                \
            _Pragma("unroll")                                         \
            for (int j_ = 0; j_ < 4; ++j_)                            \
                iacc[i_][j_] = __builtin_amdgcn_mfma_i32_16x16x64_i8( \
                    ar[i_], br[j_], iacc[i_][j_], 0, 0, 0);           \
        __builtin_amdgcn_s_setprio(0);                                \
    }

    // Steady-state vmcnt queue at BODY(s)'s wait (issue order preserved:
    // STAGEB before the asm waits, LOADA after):
    //   Bd(s+1), A(s)x4, Bd(s+2), A(s+1)x4, Bd(s+3)  = 11 outstanding.
    // WAITVM(6) pops exactly {Bd(s+1), A(s)x4} — the two things BODY(s) needs.
#define BODY(s, VMN, AC, AN, BC, BNX) {                               \
        if ((s) + 3 < NSLICE) STAGEB((s) + 3);                        \
        WAITVM(VMN);                                                  \
        BARRIER();                                                    \
        READB((s) + 1, BNX);                                          \
        WAITLGKM(4);                                                  \
        __builtin_amdgcn_sched_barrier(0);                            \
        MFMAS(AC, BC);                                                \
        if ((s) + 2 < NSLICE) LOADA((s) + 2, AC);                     \
    }

    // ---- prologue: issue order Bd0, A0, Bd1, A1, Bd2 (queue = 11) ----
    STAGEB(0); LOADA(0, aX);
    STAGEB(1); LOADA(1, aY);
    STAGEB(2);
    WAITVM(10);                 // Bd0 landed
    BARRIER();                  // publish slot 0 (+ fws_s/wsf_s)
    READB(0, bX);

    // ---- steady state: bodies 0..59 in even/odd pairs ----
    for (int s = 0; s < NSLICE - 4; s += 2) {
        BODY(s,     6, aX, aY, bX, bY);
        BODY(s + 1, 6, aY, aX, bY, bX);
    }
    // ---- tail: bodies 60..63 (vmcnt pops hand-verified) ----
    BODY(60, 6, aX, aY, bX, bY);         // STAGEB(63), LOADA(62)
    BODY(61, 5, aY, aX, bY, bX);         // LOADA(63)
    // body 62
    WAITVM(4);
    BARRIER();
    READB(63, bY);
    WAITLGKM(4);
    __builtin_amdgcn_sched_barrier(0);
    MFMAS(aX, bX);
    // body 63
    WAITVM(0);
    WAITLGKM(0);
    __builtin_amdgcn_sched_barrier(0);
    MFMAS(aY, bY);

    // --- epilogue: C/D layout col=lane&15, row=lquad*4+reg ---
    float fn[4], wf[4], bb[4];
    int ncol[4];
#pragma unroll
    for (int j = 0; j < 4; ++j) {
        const int ncl = wcl * 64 + j * 16 + lrow;
        ncol[j] = bn * BN + ncl;
        fn[j] = fws_s[ncl];
        wf[j] = wsf_s[ncl];
        bb[j] = bias[ncol[j]];
    }
    const int m0 = bm * BM + wr * 64;
#pragma unroll
    for (int i = 0; i < 4; ++i) {
#pragma unroll
        for (int r = 0; r < 4; ++r) {
            const int m = m0 + i * 16 + lquad * 4 + r;
            const float xs  = xscale[m];
            const float czp = xzpc[m];
            float* orow = out + (size_t)m * N_DIM;
#pragma unroll
            for (int j = 0; j < 4; ++j)
                orow[ncol[j]] = xs * (fn[j] * (float)iacc[i][j][r] + czp * wf[j]) + bb[j];
        }
    }
#undef BODY
#undef MFMAS
#undef READB
#undef LOADA
#undef STAGEB
}

extern "C" void kernel_launch(void* const* d_in, const int* in_sizes, int n_in,
                              void* d_out, int out_size, void* d_ws, size_t ws_size,
                              hipStream_t stream) {
    const float* x     = (const float*)d_in[0];
    const int*   qw    = (const int*)d_in[1];
    const float* wsc   = (const float*)d_in[2];
    const int*   wzp   = (const int*)d_in[3];
    const float* bias  = (const float*)d_in[4];
    float* out = (float*)d_out;

    // workspace layout
    char* A8  = (char*)d_ws;                                   //  8 MiB
    char* Bt8 = A8 + (size_t)M_DIM * K_DIM;                    // 16 MiB
    float* xscale = (float*)(Bt8 + (size_t)N_DIM * K_DIM);     //  8 KiB
    float* xzpc   = xscale + M_DIM;                            //  8 KiB
    int*   Sw     = (int*)(xzpc + M_DIM);                      // 512 KiB

    prep_kernel<<<QUANT_BLOCKS + DEQ_BLOCKS, 256, 0, stream>>>(
        x, qw, wsc, wzp, A8, Bt8, xscale, xzpc, Sw);
    dim3 grid(N_DIM / BN, M_DIM / BM);
    gemm_kernel<<<grid, 512, 0, stream>>>(A8, Bt8, xscale, xzpc, wsc, Sw, bias, out);
}

// Round 4
// 172.146 us; speedup vs baseline: 1.1410x; 1.1410x over previous
//
#include <hip/hip_runtime.h>
#include <stdint.h>

#define M_DIM 2048
#define N_DIM 4096
#define K_DIM 4096
#define NGROUP 32
#define GSIZE 128

#define RQ_UP   (127.0f / 15.0f)   // weight requant gain
#define RQ_DOWN (15.0f / 127.0f)

// ---------------------------------------------------------------------------
// R4 GEMM geometry: 128x128 tile, 256 thr (4 waves, 2Mx2N), wave 64x64 =
// 4x4 frags of 16x16x64 i8 MFMA. Grid 16x32 = 512 blocks = 2 blocks/CU
// (LDS 66 KiB <= 80). Two INDEPENDENT sync domains per CU: block A's
// barrier/waitcnt stalls overlap block B's MFMAs (m114 mechanism) — R0-R3
// all pinned at ~25% MfmaUtil with a single domain or a weak pipeline.
// Per-block pipeline = R1/R2's proven counted-vmcnt + register double-buffer:
// 4 LDS slots, prefetch distance 3, 4 DMA/stage -> steady vmcnt(8).
// LDS swizzle (verified 0 conflicts R1-R3): 16B chunk c of 64B row r at
// slot c ^ ((r>>1)&3); DMA side csrc = (lane&3) ^ ((lane>>3)&3).
// ---------------------------------------------------------------------------
#define BM 128
#define BN 128
#define KSLICE 64
#define NSLICE (K_DIM / KSLICE)    // 64
#define ASLOT (BM * KSLICE)        //  8 KiB
#define BSLOT (BN * KSLICE)        //  8 KiB

typedef __attribute__((ext_vector_type(4))) int int32x4_t;

static __device__ __forceinline__ void gl2lds16(const void* g, void* l) {
    auto gp = (const __attribute__((address_space(1))) unsigned int*)(uintptr_t)g;
    auto lp = (__attribute__((address_space(3))) unsigned int*)(uintptr_t)l;
    __builtin_amdgcn_global_load_lds(gp, lp, 16, 0, 0);
}

#define WAITVM_(N) asm volatile("s_waitcnt vmcnt(" #N ")" ::: "memory")
#define WAITVM(N) WAITVM_(N)
#define WAITLGKM_(N) asm volatile("s_waitcnt lgkmcnt(" #N ")" ::: "memory")
#define WAITLGKM(N) WAITLGKM_(N)
#define BARRIER() asm volatile("s_barrier" ::: "memory")

// ---------------------------------------------------------------------------
// Fused prep (unchanged from R2/R3 — isolate the gemm change):
//   [0, 2048): per-token activation quant -> A8 = (q-128) int8, xscale, czp
//   [2048, ..): weight requant; rsn computed in-cluster via shfl_xor max.
// ---------------------------------------------------------------------------
#define QUANT_BLOCKS M_DIM
#define DEQ_BLOCKS ((N_DIM * K_DIM) / 8 / 256)       // 8 codes / thread

__global__ __launch_bounds__(256) void prep_kernel(
        const float* __restrict__ x,
        const int* __restrict__ qw,          // [N][K] codes 0..15 as int32
        const float* __restrict__ wsc,       // [N][32]
        const int* __restrict__ wzp,         // [N][32]
        char* __restrict__ A8,               // [M][K] int8 (q-128)
        char* __restrict__ Bt8,              // [N][K] int8 requantized
        float* __restrict__ xscale,          // [M]
        float* __restrict__ xzpc,            // [M]  = 128 - zp
        int* __restrict__ Sw)                // [N][32] group sums of Bt8
{
    const int t = threadIdx.x;
    if (blockIdx.x < QUANT_BLOCKS) {
        const int s = blockIdx.x;
        const float* xrow = x + (size_t)s * K_DIM;

        float xv[16];
        float vmin = 1e38f, vmax = -1e38f;
#pragma unroll
        for (int p = 0; p < 4; ++p) {
            float4 v = *((const float4*)(xrow + p * 1024) + t);
            xv[p*4+0] = v.x; xv[p*4+1] = v.y; xv[p*4+2] = v.z; xv[p*4+3] = v.w;
            vmin = fminf(vmin, fminf(fminf(v.x, v.y), fminf(v.z, v.w)));
            vmax = fmaxf(vmax, fmaxf(fmaxf(v.x, v.y), fmaxf(v.z, v.w)));
        }
#pragma unroll
        for (int off = 32; off > 0; off >>= 1) {
            vmin = fminf(vmin, __shfl_xor(vmin, off));
            vmax = fmaxf(vmax, __shfl_xor(vmax, off));
        }
        __shared__ float smin[4], smax[4];
        const int wave = t >> 6;
        if ((t & 63) == 0) { smin[wave] = vmin; smax[wave] = vmax; }
        __syncthreads();
        vmin = fminf(fminf(smin[0], smin[1]), fminf(smin[2], smin[3]));
        vmax = fmaxf(fmaxf(smax[0], smax[1]), fmaxf(smax[2], smax[3]));

        float sc = (vmax - vmin) / 255.0f;
        sc = fmaxf(sc, 1e-5f);
        float zp = rintf(-vmin / sc);
        zp = fminf(fmaxf(zp, 0.0f), 255.0f);

#pragma unroll
        for (int p = 0; p < 4; ++p) {
            int b[4];
#pragma unroll
            for (int e = 0; e < 4; ++e) {
                float q = fminf(fmaxf(rintf(xv[p*4+e] / sc) + zp, 0.0f), 255.0f);
                b[e] = (int)q - 128;
            }
            unsigned pack = (b[0] & 0xff) | ((b[1] & 0xff) << 8) |
                            ((b[2] & 0xff) << 16) | ((b[3] & 0xff) << 24);
            *(unsigned*)(A8 + (size_t)s * K_DIM + p * 1024 + t * 4) = pack;
        }
        if (t == 0) { xscale[s] = sc; xzpc[s] = 128.0f - zp; }
    } else {
        // ---- weight requant: 8 codes/thread; 16-lane cluster = 1 group ----
        const size_t base = ((size_t)(blockIdx.x - QUANT_BLOCKS) * 256 + t) * 8;
        const int n = (int)(base >> 12);          // /4096
        const int g = (int)((base >> 7) & 31);
        const int zp = wzp[n * NGROUP + g];

        // inline rsn: row max of the 32 scales across the 16-lane cluster
        const int cl = t & 15;
        float2 wp = *(const float2*)(wsc + (size_t)n * NGROUP + cl * 2);
        float smx = fmaxf(wp.x, wp.y);
#pragma unroll
        for (int off = 1; off < 16; off <<= 1)
            smx = fmaxf(smx, __shfl_xor(smx, off));
        const float factor = wsc[n * NGROUP + g] * (RQ_UP / smx);   // <= 127/15

        int4 c0 = *(const int4*)(qw + base);
        int4 c1 = *(const int4*)(qw + base + 4);
        int w[8];
        w[0] = (int)rintf((float)(c0.x - zp) * factor);
        w[1] = (int)rintf((float)(c0.y - zp) * factor);
        w[2] = (int)rintf((float)(c0.z - zp) * factor);
        w[3] = (int)rintf((float)(c0.w - zp) * factor);
        w[4] = (int)rintf((float)(c1.x - zp) * factor);
        w[5] = (int)rintf((float)(c1.y - zp) * factor);
        w[6] = (int)rintf((float)(c1.z - zp) * factor);
        w[7] = (int)rintf((float)(c1.w - zp) * factor);
        uint2 pk;
        pk.x = (w[0] & 0xff) | ((w[1] & 0xff) << 8) | ((w[2] & 0xff) << 16) | ((w[3] & 0xff) << 24);
        pk.y = (w[4] & 0xff) | ((w[5] & 0xff) << 8) | ((w[6] & 0xff) << 16) | ((w[7] & 0xff) << 24);
        *(uint2*)(Bt8 + base) = pk;

        int s8 = w[0] + w[1] + w[2] + w[3] + w[4] + w[5] + w[6] + w[7];
#pragma unroll
        for (int off = 1; off < 16; off <<= 1) s8 += __shfl_xor(s8, off);
        if ((t & 15) == 0)
            Sw[n * NGROUP + g] = s8;     // coalesced, no atomic
    }
}

// ---------------------------------------------------------------------------
// Pipelined i8 GEMM, 2 independent blocks/CU. A and B both via LDS (4 slots),
// prefetch distance 3, fragment register double-buffer, counted vmcnt/lgkmcnt.
// Epilogue: out[m][n] = xscale[m]*(fws[n]*iacc + czp[m]*WSf[n]) + bias[n]
// ---------------------------------------------------------------------------
__global__ __launch_bounds__(256, 2) void gemm_kernel(
        const char* __restrict__ A8,     // [M][K] int8
        const char* __restrict__ Bt8,    // [N][K] int8
        const float* __restrict__ xscale,
        const float* __restrict__ xzpc,
        const float* __restrict__ wsc,   // [N][32]
        const int* __restrict__ Sw,      // [N][32]
        const float* __restrict__ bias,  // [N]
        float* __restrict__ out)         // [M][N] f32
{
    __shared__ __align__(16) char As[4][ASLOT];   // 32 KiB
    __shared__ __align__(16) char Bs[4][BSLOT];   // 32 KiB
    __shared__ float fws_s[BN], wsf_s[BN];

    const int tid  = threadIdx.x;
    const int bn   = blockIdx.x;
    const int bm   = blockIdx.y;
    const int wave = tid >> 6;           // 0..3
    const int lane = tid & 63;
    const int wr   = wave >> 1;          // 0..1 -> 64-row band
    const int wcl  = wave & 1;           // 0..1 -> 64-col band
    const int lrow  = lane & 15;
    const int lquad = lane >> 4;         // 0..3 -> 16B k-chunk

    // --- per-column epilogue constants, before the pipeline starts ---
    if (tid < BN) {
        const int n = bn * BN + tid;
        const int4* s4 = (const int4*)(Sw + (size_t)n * NGROUP);
        int acc = 0;
#pragma unroll
        for (int p = 0; p < 8; ++p) { int4 v = s4[p]; acc += v.x + v.y + v.z + v.w; }
        const float4* w4 = (const float4*)(wsc + (size_t)n * NGROUP);
        float s = 0.f;
#pragma unroll
        for (int p = 0; p < 8; ++p) {
            float4 w = w4[p];
            s = fmaxf(s, fmaxf(fmaxf(w.x, w.y), fmaxf(w.z, w.w)));
        }
        const float fw = s * RQ_DOWN;
        fws_s[tid] = fw;
        wsf_s[tid] = fw * (float)acc;
    }
    // drain everything -> uniform vmcnt/lgkmcnt baseline across waves
    asm volatile("s_waitcnt vmcnt(0) lgkmcnt(0)" ::: "memory");

    // --- staging: gl2lds dst = uniform base + lane*16 (m104). Each DMA
    // covers 16 rows x 64B; wave w instr p covers rows (p*4+w)*16.. ---
    const char* Ab = A8  + (size_t)(bm * BM) * K_DIM;
    const char* Bb = Bt8 + (size_t)(bn * BN) * K_DIM;
    const int lsub = lane >> 2;                    // row within 16-row slab
    const int csrc = (lane & 3) ^ ((lane >> 3) & 3);
    const char* gA0 = Ab + (size_t)((wave * 16     ) + lsub) * K_DIM + csrc * 16;
    const char* gA1 = Ab + (size_t)((wave * 16 + 64) + lsub) * K_DIM + csrc * 16;
    const char* gB0 = Bb + (size_t)((wave * 16     ) + lsub) * K_DIM + csrc * 16;
    const char* gB1 = Bb + (size_t)((wave * 16 + 64) + lsub) * K_DIM + csrc * 16;
    const int lOF = wave * 1024;                   // + 4096 for the +64-row slab

    // --- ds_read offsets (slot-relative), swizzle matches staging ---
    const int xq = (lquad ^ ((lrow >> 1) & 3)) * 16;
    int aoff[4], boff[4];
#pragma unroll
    for (int i = 0; i < 4; ++i)
        aoff[i] = (wr * 64 + i * 16 + lrow) * KSLICE + xq;
#pragma unroll
    for (int j = 0; j < 4; ++j)
        boff[j] = (wcl * 64 + j * 16 + lrow) * KSLICE + xq;

    int32x4_t iacc[4][4];
    const int32x4_t zi = {0, 0, 0, 0};
#pragma unroll
    for (int i = 0; i < 4; ++i)
#pragma unroll
        for (int j = 0; j < 4; ++j) iacc[i][j] = zi;

    int32x4_t aX[4], bX[4], aY[4], bY[4];

#define STAGE(t) {                                                    \
        const int sl_ = (t) & 3;                                      \
        const size_t k0_ = (size_t)(t) * KSLICE;                      \
        gl2lds16(gA0 + k0_, &As[sl_][0] + lOF);                       \
        gl2lds16(gA1 + k0_, &As[sl_][0] + 4096 + lOF);                \
        gl2lds16(gB0 + k0_, &Bs[sl_][0] + lOF);                       \
        gl2lds16(gB1 + k0_, &Bs[sl_][0] + 4096 + lOF);                \
    }

#define READF(t, af, bf) {                                            \
        const char* Ap_ = &As[(t) & 3][0];                            \
        const char* Bp_ = &Bs[(t) & 3][0];                            \
        _Pragma("unroll")                                             \
        for (int i_ = 0; i_ < 4; ++i_)                                \
            af[i_] = *(const int32x4_t*)(Ap_ + aoff[i_]);             \
        _Pragma("unroll")                                             \
        for (int j_ = 0; j_ < 4; ++j_)                                \
            bf[j_] = *(const int32x4_t*)(Bp_ + boff[j_]);             \
    }

#define MFMAS(af, bf) {                                               \
        __builtin_amdgcn_s_setprio(1);                                \
        _Pragma("unroll")                                             \
        for (int i_ = 0; i_ < 4; ++i_)                                \
            _Pragma("unroll")                                         \
            for (int j_ = 0; j_ < 4; ++j_)                            \
                iacc[i_][j_] = __builtin_amdgcn_mfma_i32_16x16x64_i8( \
                    af[i_], bf[j_], iacc[i_][j_], 0, 0, 0);           \
        __builtin_amdgcn_s_setprio(0);                                \
    }

    // Steady-state vmcnt queue at BODY(s)'s wait: stages s+1, s+2, s+3
    // outstanding (4 DMA each) = 12; WAITVM(8) pops stage(s+1) — the slot
    // the following barrier publishes for READF(s+1).
#define BODY(s, VMN, CA, CB, NA, NB) {                                \
        if ((s) + 3 < NSLICE) STAGE((s) + 3);                         \
        WAITVM(VMN);                                                  \
        BARRIER();                                                    \
        READF((s) + 1, NA, NB);                                       \
        WAITLGKM(8);                                                  \
        __builtin_amdgcn_sched_barrier(0);                            \
        MFMAS(CA, CB);                                                \
        BARRIER();                                                    \
    }

    // ---- prologue: 12 DMAs in flight; land stage 0; read frags(0) ----
    STAGE(0); STAGE(1); STAGE(2);
    WAITVM(8);                  // stage 0 landed (this wave's 4)
    BARRIER();                  // publish slot 0 (+ fws_s/wsf_s)
    READF(0, aX, bX);

    // ---- steady state: bodies 0..59 in even/odd pairs ----
    for (int s = 0; s < NSLICE - 4; s += 2) {
        BODY(s,     8, aX, bX, aY, bY);
        BODY(s + 1, 8, aY, bY, aX, bX);
    }
    // ---- tail: bodies 60..63 ----
    BODY(60, 8, aX, bX, aY, bY);         // stages 63; outstanding 61,62,63
    BODY(61, 4, aY, bY, aX, bX);         // outstanding 62,63 -> wait 62
    // body 62: land stage 63, read frags(63), MFMA(62)
    WAITVM(0);
    BARRIER();
    READF(63, aY, bY);
    WAITLGKM(8);
    __builtin_amdgcn_sched_barrier(0);
    MFMAS(aX, bX);
    // body 63: final MFMA
    WAITLGKM(0);
    __builtin_amdgcn_sched_barrier(0);
    MFMAS(aY, bY);

    // --- epilogue: C/D layout col=lane&15, row=lquad*4+reg ---
    float fn[4], wf[4], bb[4];
    int ncol[4];
#pragma unroll
    for (int j = 0; j < 4; ++j) {
        const int ncl = wcl * 64 + j * 16 + lrow;
        ncol[j] = bn * BN + ncl;
        fn[j] = fws_s[ncl];
        wf[j] = wsf_s[ncl];
        bb[j] = bias[ncol[j]];
    }
    const int m0 = bm * BM + wr * 64;
#pragma unroll
    for (int i = 0; i < 4; ++i) {
#pragma unroll
        for (int r = 0; r < 4; ++r) {
            const int m = m0 + i * 16 + lquad * 4 + r;
            const float xs  = xscale[m];
            const float czp = xzpc[m];
            float* orow = out + (size_t)m * N_DIM;
#pragma unroll
            for (int j = 0; j < 4; ++j)
                orow[ncol[j]] = xs * (fn[j] * (float)iacc[i][j][r] + czp * wf[j]) + bb[j];
        }
    }
#undef BODY
#undef MFMAS
#undef READF
#undef STAGE
}

extern "C" void kernel_launch(void* const* d_in, const int* in_sizes, int n_in,
                              void* d_out, int out_size, void* d_ws, size_t ws_size,
                              hipStream_t stream) {
    const float* x     = (const float*)d_in[0];
    const int*   qw    = (const int*)d_in[1];
    const float* wsc   = (const float*)d_in[2];
    const int*   wzp   = (const int*)d_in[3];
    const float* bias  = (const float*)d_in[4];
    float* out = (float*)d_out;

    // workspace layout
    char* A8  = (char*)d_ws;                                   //  8 MiB
    char* Bt8 = A8 + (size_t)M_DIM * K_DIM;                    // 16 MiB
    float* xscale = (float*)(Bt8 + (size_t)N_DIM * K_DIM);     //  8 KiB
    float* xzpc   = xscale + M_DIM;                            //  8 KiB
    int*   Sw     = (int*)(xzpc + M_DIM);                      // 512 KiB

    prep_kernel<<<QUANT_BLOCKS + DEQ_BLOCKS, 256, 0, stream>>>(
        x, qw, wsc, wzp, A8, Bt8, xscale, xzpc, Sw);
    dim3 grid(N_DIM / BN, M_DIM / BM);
    gemm_kernel<<<grid, 256, 0, stream>>>(A8, Bt8, xscale, xzpc, wsc, Sw, bias, out);
}